// Round 1
// baseline (144.658 us; speedup 1.0000x reference)
//
#include <hip/hip_runtime.h>
#include <stdint.h>

#define BATCHES 64
#define IMG_H 512
#define IMG_W 512
#define PS 8
#define NP 32
#define NPOS_W 505
#define NPOS_H 505
#define NPOS (NPOS_H * NPOS_W) /* 255025 */
#define CHUNKS 32
#define NSORT 1024

// Monotone float->uint transform: order of uints == order of floats.
__device__ __forceinline__ unsigned int f2sortable(float f) {
    unsigned int u = __float_as_uint(f);
    return (u & 0x80000000u) ? ~u : (u | 0x80000000u);
}

// Pass 1: compact all center values > 3.0 into per-batch candidate lists.
// key = (sortable_val << 32) | ~idx  -> sorting keys descending gives exactly
// jax top_k order (value desc, lower index first on ties).
__global__ __launch_bounds__(256) void collect_kernel(
    const float* __restrict__ x,
    int* __restrict__ counts,
    unsigned long long* __restrict__ cands,
    int cap) {
    const int b = blockIdx.x >> 5;        // 32 chunks per batch
    const int chunk = blockIdx.x & 31;
    const float* img = x + (size_t)b * (IMG_H * IMG_W);
    for (int q = chunk * 256 + threadIdx.x; q < NPOS; q += CHUNKS * 256) {
        unsigned int i = (unsigned int)q / NPOS_W;
        unsigned int j = (unsigned int)q - i * NPOS_W;
        float v = img[(i + 4) * IMG_W + (j + 4)];
        if (v > 3.0f) {
            int slot = atomicAdd(&counts[b], 1);
            if (slot < cap) {
                unsigned long long key =
                    ((unsigned long long)f2sortable(v) << 32) |
                    (unsigned long long)(unsigned int)(~(unsigned int)q);
                cands[(size_t)b * cap + slot] = key;
            }
        }
    }
}

// Pass 2: per batch, exact top-32 of candidates (bitonic sort in LDS),
// then gather the 32 8x8 patches. Slow exact fallback if candidate count
// is out of range (statistically never taken).
__global__ __launch_bounds__(256) void select_gather_kernel(
    const float* __restrict__ x,
    const int* __restrict__ counts,
    const unsigned long long* __restrict__ cands,
    float* __restrict__ out,
    int cap) {
    __shared__ unsigned long long skeys[NSORT];
    __shared__ unsigned long long topk[NP];
    const int b = blockIdx.x;
    const int tid = threadIdx.x;
    const float* img = x + (size_t)b * (IMG_H * IMG_W);
    const int count = counts[b];
    const bool fast = (count >= NP) && (count <= cap) && (cap >= NP);

    if (fast) {
        for (int i = tid; i < NSORT; i += 256)
            skeys[i] = (i < count) ? cands[(size_t)b * cap + i] : 0ull;
        __syncthreads();
        // Bitonic sort, descending.
        for (int k = 2; k <= NSORT; k <<= 1) {
            for (int j = k >> 1; j > 0; j >>= 1) {
                for (int i = tid; i < NSORT; i += 256) {
                    int ixj = i ^ j;
                    if (ixj > i) {
                        unsigned long long a = skeys[i];
                        unsigned long long c = skeys[ixj];
                        bool descending = ((i & k) == 0);
                        if ((a < c) == descending) { skeys[i] = c; skeys[ixj] = a; }
                    }
                }
                __syncthreads();
            }
        }
        if (tid < NP) topk[tid] = skeys[tid];
        __syncthreads();
    } else {
        // Exact slow path: 32 iterations of block-wide max over all centers,
        // strictly below the previously selected key.
        unsigned long long prev = 0xFFFFFFFFFFFFFFFFull;
        for (int sel = 0; sel < NP; ++sel) {
            unsigned long long best = 0ull;
            for (int q = tid; q < NPOS; q += 256) {
                unsigned int i = (unsigned int)q / NPOS_W;
                unsigned int j = (unsigned int)q - i * NPOS_W;
                float v = img[(i + 4) * IMG_W + (j + 4)];
                unsigned long long key =
                    ((unsigned long long)f2sortable(v) << 32) |
                    (unsigned long long)(unsigned int)(~(unsigned int)q);
                if (key < prev && key > best) best = key;
            }
            skeys[tid] = best;
            __syncthreads();
            for (int s = 128; s > 0; s >>= 1) {
                if (tid < s) {
                    if (skeys[tid + s] > skeys[tid]) skeys[tid] = skeys[tid + s];
                }
                __syncthreads();
            }
            best = skeys[0];
            if (tid == 0) topk[sel] = best;
            prev = best;
            __syncthreads();
        }
    }

    // Gather: 32 patches x 64 elements = 2048 coalesced output writes.
    for (int e = tid; e < NP * PS * PS; e += 256) {
        int p = e >> 6;
        int rem = e & 63;
        int pi = rem >> 3;
        int pj = rem & 7;
        unsigned int q = ~(unsigned int)(topk[p] & 0xFFFFFFFFull);
        unsigned int r = q / NPOS_W;
        unsigned int c = q - r * NPOS_W;
        out[((size_t)b * NP + p) * (PS * PS) + rem] = img[(r + pi) * IMG_W + (c + pj)];
    }
}

extern "C" void kernel_launch(void* const* d_in, const int* in_sizes, int n_in,
                              void* d_out, int out_size, void* d_ws, size_t ws_size,
                              hipStream_t stream) {
    const float* x = (const float*)d_in[0];
    float* out = (float*)d_out;

    int* counts = (int*)d_ws;
    unsigned long long* cands = (unsigned long long*)((char*)d_ws + 1024);
    int cap = 0;
    if (ws_size > 1024) {
        size_t c = (ws_size - 1024) / ((size_t)BATCHES * sizeof(unsigned long long));
        cap = (int)(c > (size_t)NSORT ? (size_t)NSORT : c);
    }

    hipMemsetAsync(counts, 0, BATCHES * sizeof(int), stream);
    collect_kernel<<<dim3(BATCHES * CHUNKS), dim3(256), 0, stream>>>(x, counts, cands, cap);
    select_gather_kernel<<<dim3(BATCHES), dim3(256), 0, stream>>>(x, counts, cands, out, cap);
}